// Round 2
// baseline (4123.383 us; speedup 1.0000x reference)
//
#include <hip/hip_runtime.h>
#include <math.h>

#define TDIM 36
#define PDIM 161        // 2*80+1 atoms
#define PPAD 172        // x/y/Ds column pad: 43 float4 quads, bank-friendly stride
#define TPAD 44         // t pad for Dt/Yc/Rs rows
#define DTROWS 172      // Dt padded row count (phase-B p-tiles reach p=169)
#define NCOL 50
#define NITER 100
#define PITER 400       // power-iteration steps on 36x36 Gram (multiple of 4)
#define PPAD_S 164      // setup-kernel D row stride (41 quads)

// ---------------- setup: build D, normalize, lambda_max via Gram power iteration -------
// G = D D^T (36x36) has the same nonzero spectrum as D^T D (161x161) but each power
// step is a 36-dot per lane of ONE wave, G held in registers -> no barriers in the loop.

__global__ __launch_bounds__(256)
void setup_kernel(const float* __restrict__ rho, const float* __restrict__ theta,
                  float* __restrict__ wsD, float* __restrict__ wsS,
                  float* __restrict__ dic)
{
  __shared__ float Dl[TDIM][PPAD_S];
  __shared__ float Gs[64][40];        // rows 36..63 zero so lanes 36..63 compute 0
  __shared__ float vS[40];
  const int tid = threadIdx.x;

  // zero-init D pads and G
  for (int i = tid; i < TDIM * PPAD_S; i += 256) ((float*)Dl)[i] = 0.0f;
  for (int i = tid; i < 64 * 40; i += 256) ((float*)Gs)[i] = 0.0f;
  __syncthreads();

  // build one dictionary column per thread (col 0 = ones, unnormalized per reference)
  if (tid < PDIM) {
    if (tid == 0) {
      for (int t = 0; t < TDIM; ++t) Dl[t][0] = 1.0f;
    } else {
      const bool is_sin = tid > 80;
      const int n = is_sin ? (tid - 81) : (tid - 1);
      const float rr = 0.001f + 1.149f / (1.0f + expf(-rho[n]));
      const float th = 3.14159265358979f / (1.0f + expf(-theta[n]));
      const float lr = logf(rr);
      float s2 = 0.0f;
      for (int t = 0; t < TDIM; ++t) {
        const float ft = (float)t;
        const float pw = expf(ft * lr);
        const float ang = ft * th;
        const float val = pw * (is_sin ? sinf(ang) : cosf(ang));
        Dl[t][tid] = val;
        s2 += val * val;
      }
      const float inv = 1.0f / sqrtf(s2);
      for (int t = 0; t < TDIM; ++t) Dl[t][tid] *= inv;
    }
  }
  __syncthreads();

  // write normalized D to workspace and dic output
  for (int i = tid; i < TDIM * PDIM; i += 256) {
    const int t = i / PDIM, p = i - t * PDIM;
    const float val = Dl[t][p];
    wsD[i] = val;
    dic[i] = val;
  }

  // Gram: Gs[i][j] = dot(D row i, D row j) over 164 (pads are zero)
  for (int idx = tid; idx < TDIM * TDIM; idx += 256) {
    const int i = idx / TDIM, j = idx - i * TDIM;
    const float4* ri = (const float4*)&Dl[i][0];
    const float4* rj = (const float4*)&Dl[j][0];
    float a = 0.0f;
    #pragma unroll 8
    for (int k = 0; k < PPAD_S / 4; ++k) {
      const float4 x = ri[k], y = rj[k];
      a += x.x * y.x + x.y * y.y + x.z * y.z + x.w * y.w;
    }
    Gs[i][j] = a;
  }
  __syncthreads();

  // single-wave power iteration; other waves exit (no barriers below)
  if (tid < 64) {
    const int lane = tid;
    float g[36];
    #pragma unroll
    for (int j = 0; j < 36; ++j) g[j] = Gs[lane][j];   // zero rows for lanes >= 36
    if (lane < 40) vS[lane] = (lane < 36) ? 1.0f : 0.0f;
    __asm__ __volatile__("s_waitcnt lgkmcnt(0)" ::: "memory");

    for (int it = 0; it < PITER; ++it) {
      float w = 0.0f;
      #pragma unroll
      for (int j = 0; j < 36; ++j) w += g[j] * vS[j];  // broadcast LDS reads
      float nw = w;
      if ((it & 3) == 3) {                             // renormalize every 4 steps
        float s = w * w;
        #pragma unroll
        for (int off = 32; off > 0; off >>= 1) s += __shfl_xor(s, off, 64);
        nw = w * rsqrtf(s);
      }
      if (lane < 40) vS[lane] = (lane < 36) ? nw : 0.0f;
      __asm__ __volatile__("s_waitcnt lgkmcnt(0)" ::: "memory");
    }
    // v is unit (PITER-1 renormalized); Rayleigh quotient lam = v.Gv
    float w = 0.0f;
    #pragma unroll
    for (int j = 0; j < 36; ++j) w += g[j] * vS[j];
    float num = (lane < 36) ? vS[lane] * w : 0.0f;
    #pragma unroll
    for (int off = 32; off > 0; off >>= 1) num += __shfl_xor(num, off, 64);
    if (lane == 0) {
      const float li = 1.0f / num;      // L_inv = 1/lambda_max(DtD)
      wsS[0] = li;
      wsS[1] = 0.1f * li;               // thr = lam_f * L_inv
    }
  }
}

// ---------------- main: per-batch FISTA, all state resident in LDS ---------------------
// x_new = shrink(y + L_inv * D^T (Y - D y), thr)

__device__ __forceinline__ float shrink_upd(float w, float thr, float ttf,
                                            float xold, float& ynew) {
  float a = fabsf(w) - thr;
  a = a > 0.0f ? a : 0.0f;
  const float xn = copysignf(a, w);
  ynew = (1.0f + ttf) * xn - ttf * xold;
  return xn;
}

__global__ __launch_bounds__(512, 2)
void fista_kernel(const float* __restrict__ xin, const float* __restrict__ wsD,
                  const float* __restrict__ wsS, float* __restrict__ outC,
                  float* __restrict__ outR)
{
  extern __shared__ float sm[];
  float* Ds = sm;                        // [TDIM][PPAD]   D, p-contiguous
  float* Dt = Ds + TDIM * PPAD;          // [DTROWS][TPAD] D^T, t-contiguous
  float* Yc = Dt + DTROWS * TPAD;        // [NCOL][TPAD]
  float* Rs = Yc + NCOL * TPAD;          // [NCOL][TPAD]
  float* Xs = Rs + NCOL * TPAD;          // [NCOL][PPAD]
  float* Ys = Xs + NCOL * PPAD;          // [NCOL][PPAD]

  const int tid = threadIdx.x;
  const int b = blockIdx.x;
  const float L_inv = wsS[0];
  const float thr = wsS[1];

  // ---- stage
  for (int i = tid; i < TDIM * PPAD; i += 512) {
    const int t = i / PPAD, p = i - t * PPAD;
    Ds[i] = (p < PDIM) ? wsD[t * PDIM + p] : 0.0f;
  }
  for (int i = tid; i < DTROWS * TPAD; i += 512) {
    const int p = i / TPAD, t = i - p * TPAD;
    Dt[i] = (p < PDIM && t < TDIM) ? wsD[t * PDIM + p] : 0.0f;
  }
  const float* xb = xin + b * TDIM * NCOL;
  for (int i = tid; i < NCOL * TPAD; i += 512) {
    const int c = i / TPAD, t = i - c * TPAD;
    Yc[i] = (t < TDIM) ? xb[t * NCOL + c] : 0.0f;
  }
  for (int i = tid; i < NCOL * PPAD; i += 512) { Xs[i] = 0.0f; Ys[i] = 0.0f; }
  __syncthreads();

  // phase A: one wave, 6t x 5c tiles (6 t-tiles x 10 c-tiles = 60 threads)
  const int s1c = tid / 6, s1t = tid - 6 * s1c;       // lane = s1c*6 + s1t
  const bool act1 = tid < 60;
  const int t0 = 6 * s1t, c0a = 5 * s1c;
  // phase B: 3 waves, 10p x 5c tiles (17 p-tiles x 10 c-tiles = 170 threads)
  const int s2p = tid / 10, s2c = tid - 10 * s2p;     // lane group of 10 shares p
  const bool act2 = tid < 170;
  const int p0 = 10 * s2p, c0b = 5 * s2c;

  float tk = 1.0f;

  for (int it = 0; it < NITER; ++it) {
    // ---- phase A: Rs[c][t] = Yc[c][t] - sum_p Ds[t][p] * Ys[c][p]
    if (act1) {
      float acc[6][5];
      #pragma unroll
      for (int i = 0; i < 6; ++i)
        #pragma unroll
        for (int j = 0; j < 5; ++j) acc[i][j] = 0.0f;
      #pragma unroll 4
      for (int k = 0; k < PPAD / 4; ++k) {
        float4 dv[6], yv[5];
        #pragma unroll
        for (int i = 0; i < 6; ++i) dv[i] = *(const float4*)(Ds + (t0 + i) * PPAD + 4 * k);
        #pragma unroll
        for (int j = 0; j < 5; ++j) yv[j] = *(const float4*)(Ys + (c0a + j) * PPAD + 4 * k);
        #pragma unroll
        for (int i = 0; i < 6; ++i)
          #pragma unroll
          for (int j = 0; j < 5; ++j)
            acc[i][j] += dv[i].x * yv[j].x + dv[i].y * yv[j].y
                       + dv[i].z * yv[j].z + dv[i].w * yv[j].w;
      }
      #pragma unroll
      for (int j = 0; j < 5; ++j)
        #pragma unroll
        for (int i = 0; i < 6; ++i)
          Rs[(c0a + j) * TPAD + t0 + i] = Yc[(c0a + j) * TPAD + t0 + i] - acc[i][j];
    }
    __syncthreads();

    const float tnew = 0.5f * (1.0f + sqrtf(1.0f + 4.0f * tk * tk));
    const float ttf = (tk - 1.0f) / tnew;
    tk = tnew;

    // ---- phase B: w = y + L_inv * D^T r ; shrink + momentum
    if (act2) {
      float acc[10][5];
      #pragma unroll
      for (int i = 0; i < 10; ++i)
        #pragma unroll
        for (int j = 0; j < 5; ++j) acc[i][j] = 0.0f;
      #pragma unroll
      for (int k = 0; k < TDIM / 4; ++k) {
        float4 dv[10], rv[5];
        #pragma unroll
        for (int i = 0; i < 10; ++i) dv[i] = *(const float4*)(Dt + (p0 + i) * TPAD + 4 * k);
        #pragma unroll
        for (int j = 0; j < 5; ++j) rv[j] = *(const float4*)(Rs + (c0b + j) * TPAD + 4 * k);
        #pragma unroll
        for (int i = 0; i < 10; ++i)
          #pragma unroll
          for (int j = 0; j < 5; ++j)
            acc[i][j] += dv[i].x * rv[j].x + dv[i].y * rv[j].y
                       + dv[i].z * rv[j].z + dv[i].w * rv[j].w;
      }
      #pragma unroll
      for (int j = 0; j < 5; ++j) {
        const int c = c0b + j;
        #pragma unroll
        for (int h = 0; h < 5; ++h) {            // float2 over p (p0 is even)
          float* yp = Ys + c * PPAD + p0 + 2 * h;
          float* xp = Xs + c * PPAD + p0 + 2 * h;
          const float2 yv = *(const float2*)yp;
          const float2 xv = *(const float2*)xp;
          const float w0 = yv.x + L_inv * acc[2 * h][j];
          const float w1 = yv.y + L_inv * acc[2 * h + 1][j];
          float yn0, yn1;
          const float x0 = shrink_upd(w0, thr, ttf, xv.x, yn0);
          const float x1 = shrink_upd(w1, thr, ttf, xv.y, yn1);
          *(float2*)xp = make_float2(x0, x1);
          *(float2*)yp = make_float2(yn0, yn1);
        }
      }
    }
    __syncthreads();
  }

  // ---- outputs: C = x_fin
  float* Cb = outC + b * PDIM * NCOL;
  for (int i = tid; i < PDIM * NCOL; i += 512) {
    const int p = i / NCOL, c = i - p * NCOL;
    Cb[i] = Xs[c * PPAD + p];
  }
  // reconst = D @ C (phase-A tiling on Xs)
  if (act1) {
    float acc[6][5];
    #pragma unroll
    for (int i = 0; i < 6; ++i)
      #pragma unroll
      for (int j = 0; j < 5; ++j) acc[i][j] = 0.0f;
    #pragma unroll 4
    for (int k = 0; k < PPAD / 4; ++k) {
      float4 dv[6], yv[5];
      #pragma unroll
      for (int i = 0; i < 6; ++i) dv[i] = *(const float4*)(Ds + (t0 + i) * PPAD + 4 * k);
      #pragma unroll
      for (int j = 0; j < 5; ++j) yv[j] = *(const float4*)(Xs + (c0a + j) * PPAD + 4 * k);
      #pragma unroll
      for (int i = 0; i < 6; ++i)
        #pragma unroll
        for (int j = 0; j < 5; ++j)
          acc[i][j] += dv[i].x * yv[j].x + dv[i].y * yv[j].y
                     + dv[i].z * yv[j].z + dv[i].w * yv[j].w;
    }
    float* Rb = outR + b * TDIM * NCOL;
    #pragma unroll
    for (int i = 0; i < 6; ++i)
      #pragma unroll
      for (int j = 0; j < 5; ++j)
        Rb[(t0 + i) * NCOL + c0a + j] = acc[i][j];
  }
}

// ---------------- launch --------------------------------------------------------------

extern "C" void kernel_launch(void* const* d_in, const int* in_sizes, int n_in,
                              void* d_out, int out_size, void* d_ws, size_t ws_size,
                              hipStream_t stream) {
  const float* x     = (const float*)d_in[0];   // (256, 36, 50)
  const float* rho   = (const float*)d_in[1];   // (80,)
  const float* theta = (const float*)d_in[2];   // (80,)

  float* out    = (float*)d_out;
  float* outC   = out;                              // 256*161*50
  float* outDic = out + 256 * PDIM * NCOL;          // 36*161
  float* outR   = outDic + TDIM * PDIM;             // 256*36*50

  float* wsD = (float*)d_ws;                        // 36*161 normalized dictionary
  float* wsS = wsD + TDIM * PDIM;                   // [L_inv, thr]

  hipLaunchKernelGGL(setup_kernel, dim3(1), dim3(256), 0, stream,
                     rho, theta, wsD, wsS, outDic);

  const size_t smem = (size_t)(TDIM * PPAD + DTROWS * TPAD + 2 * NCOL * TPAD
                               + 2 * NCOL * PPAD) * sizeof(float);  // 141,440 B
  hipLaunchKernelGGL(fista_kernel, dim3(256), dim3(512), smem, stream,
                     x, wsD, wsS, outC, outR);
}

// Round 3
// 431.107 us; speedup vs baseline: 9.5646x; 9.5646x over previous
//
#include <hip/hip_runtime.h>
#include <math.h>

typedef _Float16 half_t;
typedef __attribute__((ext_vector_type(8))) _Float16 half8;
typedef __attribute__((ext_vector_type(4))) _Float16 half4;
typedef __attribute__((ext_vector_type(4))) float floatx4;

#define TDIM 36
#define PDIM 161        // 2*80+1 atoms
#define NCOL 50
#define NITER 100
#define PITER 400       // power-iteration steps on 36x36 Gram
#define PPAD_S 164      // setup-kernel D row stride

// fista LDS geometry (fp16 units). K_A = p padded to 192 (6 steps of 32);
// K_B = t padded to 64 (2 steps of 32).
#define PKS 200   // row stride of p-contiguous arrays: 400 B = 100 dw, %32=4 -> 2-way banks
#define TKS 72    // row stride of t-contiguous arrays: 144 B = 36 dw, %32=4 -> 2-way banks
#define NKA 6
#define NKB 2

// LDS offsets (fp16 units). Dh/Dl are staging-only and ALIAS the Yh/Yl region
// (frag-cached into registers before Y is zeroed).
#define OFF_YH  0                       // [64][PKS]  y^T hi   (B operand, phase A)
#define OFF_YL  12800                   // [64][PKS]  y^T lo
#define OFF_DTH 25600                   // [176][TKS] D^T hi   (A operand, phase B)
#define OFF_DTL 38272                   // [176][TKS] D^T lo
#define OFF_RH  50944                   // [64][TKS]  R^T hi   (B operand, phase B)
#define OFF_RL  55552                   // [64][TKS]  R^T lo
#define LDS_FP16_TOTAL 60160            // 120,320 bytes
#define OFF_DH  0                       // [48][PKS]  D hi (staging alias)
#define OFF_DL  9600                    // [48][PKS]  D lo (staging alias)

// ---------------- setup: build D, normalize, lambda_max via Gram power iteration -------

__global__ __launch_bounds__(256)
void setup_kernel(const float* __restrict__ rho, const float* __restrict__ theta,
                  float* __restrict__ wsD, float* __restrict__ wsS,
                  float* __restrict__ dic)
{
  __shared__ float Dl[TDIM][PPAD_S];
  __shared__ float Gs[64][40];
  __shared__ float vS[40];
  const int tid = threadIdx.x;

  for (int i = tid; i < TDIM * PPAD_S; i += 256) ((float*)Dl)[i] = 0.0f;
  for (int i = tid; i < 64 * 40; i += 256) ((float*)Gs)[i] = 0.0f;
  __syncthreads();

  if (tid < PDIM) {
    if (tid == 0) {
      for (int t = 0; t < TDIM; ++t) Dl[t][0] = 1.0f;
    } else {
      const bool is_sin = tid > 80;
      const int n = is_sin ? (tid - 81) : (tid - 1);
      const float rr = 0.001f + 1.149f / (1.0f + expf(-rho[n]));
      const float th = 3.14159265358979f / (1.0f + expf(-theta[n]));
      const float lr = logf(rr);
      float s2 = 0.0f;
      for (int t = 0; t < TDIM; ++t) {
        const float ft = (float)t;
        const float pw = expf(ft * lr);
        const float ang = ft * th;
        const float val = pw * (is_sin ? sinf(ang) : cosf(ang));
        Dl[t][tid] = val;
        s2 += val * val;
      }
      const float inv = 1.0f / sqrtf(s2);
      for (int t = 0; t < TDIM; ++t) Dl[t][tid] *= inv;
    }
  }
  __syncthreads();

  for (int i = tid; i < TDIM * PDIM; i += 256) {
    const int t = i / PDIM, p = i - t * PDIM;
    const float val = Dl[t][p];
    wsD[i] = val;
    dic[i] = val;
  }

  // Gram G = D D^T (same nonzero spectrum as DtD)
  for (int idx = tid; idx < TDIM * TDIM; idx += 256) {
    const int i = idx / TDIM, j = idx - i * TDIM;
    const float4* ri = (const float4*)&Dl[i][0];
    const float4* rj = (const float4*)&Dl[j][0];
    float a = 0.0f;
    #pragma unroll 8
    for (int k = 0; k < PPAD_S / 4; ++k) {
      const float4 x = ri[k], y = rj[k];
      a += x.x * y.x + x.y * y.y + x.z * y.z + x.w * y.w;
    }
    Gs[i][j] = a;
  }
  __syncthreads();

  if (tid < 64) {
    const int lane = tid;
    float g[36];
    #pragma unroll
    for (int j = 0; j < 36; ++j) g[j] = Gs[lane][j];
    if (lane < 40) vS[lane] = (lane < 36) ? 1.0f : 0.0f;
    __asm__ __volatile__("s_waitcnt lgkmcnt(0)" ::: "memory");

    for (int it = 0; it < PITER; ++it) {
      float w = 0.0f;
      #pragma unroll
      for (int j = 0; j < 36; ++j) w += g[j] * vS[j];
      float nw = w;
      if ((it & 3) == 3) {
        float s = w * w;
        #pragma unroll
        for (int off = 32; off > 0; off >>= 1) s += __shfl_xor(s, off, 64);
        nw = w * rsqrtf(s);
      }
      if (lane < 40) vS[lane] = (lane < 36) ? nw : 0.0f;
      __asm__ __volatile__("s_waitcnt lgkmcnt(0)" ::: "memory");
    }
    float w = 0.0f;
    #pragma unroll
    for (int j = 0; j < 36; ++j) w += g[j] * vS[j];
    float num = (lane < 36) ? vS[lane] * w : 0.0f;
    #pragma unroll
    for (int off = 32; off > 0; off >>= 1) num += __shfl_xor(num, off, 64);
    if (lane == 0) {
      const float li = 1.0f / num;
      wsS[0] = li;
      wsS[1] = 0.1f * li;
    }
  }
}

// ---------------- main: MFMA FISTA, fp16 hi/lo split (3-term products ~= fp32) ---------
// Phase A: R = Y - D y     (GEMM M=t 48, N=c 64, K=p 192)
// Phase B: w = y + L_inv D^T R ; x = shrink(w); y = (1+ttf)x - ttf x_old
//                          (GEMM M=p 176, N=c 64, K=t 64)
// Fragment layouts (gfx950 16x16x32): A[m=lane&15][k=quad*8+j];
// B[k=quad*8+j][n=lane&15]; C/D col=lane&15, row=quad*4+reg.

__global__ __launch_bounds__(512)
void fista_kernel(const float* __restrict__ xin, const float* __restrict__ wsD,
                  const float* __restrict__ wsS, float* __restrict__ outC,
                  float* __restrict__ outR)
{
  extern __shared__ char smc[];
  half_t* sh  = (half_t*)smc;
  half_t* Yh  = sh + OFF_YH;
  half_t* Yl  = sh + OFF_YL;
  half_t* Dth = sh + OFF_DTH;
  half_t* Dtl = sh + OFF_DTL;
  half_t* Rh  = sh + OFF_RH;
  half_t* Rl  = sh + OFF_RL;
  half_t* Dh  = sh + OFF_DH;   // staging alias of Yh/Yl region
  half_t* Dl  = sh + OFF_DL;

  const int tid = threadIdx.x;
  const int b = blockIdx.x;
  const int wave = tid >> 6, lane = tid & 63;
  const int q = lane >> 4, ln = lane & 15;
  const float L_inv = wsS[0];
  const float thr = wsS[1];

  // ---- zero all LDS (pads must be 0)
  {
    unsigned int* z = (unsigned int*)smc;
    for (int i = tid; i < LDS_FP16_TOTAL / 2; i += 512) z[i] = 0u;
  }
  __syncthreads();
  // ---- stage D hi/lo in both layouts
  for (int i = tid; i < TDIM * PDIM; i += 512) {
    const int t = i / PDIM, p = i - t * PDIM;
    const float v = wsD[i];
    const half_t h = (half_t)v;
    const half_t l = (half_t)(v - (float)h);
    Dh[t * PKS + p] = h;   Dl[t * PKS + p] = l;
    Dth[p * TKS + t] = h;  Dtl[p * TKS + t] = l;
  }
  __syncthreads();

  // ---- ownership
  // phase A (waves 0..5): m-tile mtA = wave>>1 (t rows), n-tiles {ntA, ntA+1}
  const int mtA = wave >> 1;
  const int ntA = (wave & 1) * 2;
  // phase B (all 8): n-tile pair from wave&1; m-tiles {gB, gB+4, gB+8} (gB==3 -> 2)
  const int gB = wave >> 1;
  const int nTB = (gB == 3) ? 2 : 3;
  const int nB0 = 32 * (wave & 1) + ln;   // C column / B-operand n for j=0

  // ---- cache loop-invariant A-fragments in registers
  half8 DhF[NKA], DlF[NKA];
  if (wave < 6) {
    const int row = 16 * mtA + ln;
    #pragma unroll
    for (int ks = 0; ks < NKA; ++ks) {
      DhF[ks] = *(const half8*)(Dh + row * PKS + 32 * ks + 8 * q);
      DlF[ks] = *(const half8*)(Dl + row * PKS + 32 * ks + 8 * q);
    }
  }
  half8 DtHF[3][NKB], DtLF[3][NKB];
  #pragma unroll
  for (int ti = 0; ti < 3; ++ti) {
    if (ti < nTB) {
      const int row = 16 * (gB + 4 * ti) + ln;
      #pragma unroll
      for (int ks = 0; ks < NKB; ++ks) {
        DtHF[ti][ks] = *(const half8*)(Dth + row * TKS + 32 * ks + 8 * q);
        DtLF[ti][ks] = *(const half8*)(Dtl + row * TKS + 32 * ks + 8 * q);
      }
    }
  }

  // ---- static Y (fp32) at this lane's phase-A C positions
  float yA[2][4];
  if (wave < 6) {
    const float* xb = xin + b * TDIM * NCOL;
    #pragma unroll
    for (int j = 0; j < 2; ++j) {
      const int c = 16 * (ntA + j) + ln;
      #pragma unroll
      for (int r = 0; r < 4; ++r) {
        const int t = 16 * mtA + 4 * q + r;
        yA[j][r] = (t < TDIM && c < NCOL) ? xb[t * NCOL + c] : 0.0f;
      }
    }
  }

  // ---- register-resident FISTA state at this lane's phase-B C positions
  float xR[3][2][4], yR[3][2][4];
  #pragma unroll
  for (int ti = 0; ti < 3; ++ti)
    #pragma unroll
    for (int j = 0; j < 2; ++j)
      #pragma unroll
      for (int r = 0; r < 4; ++r) { xR[ti][j][r] = 0.0f; yR[ti][j][r] = 0.0f; }

  __syncthreads();       // frag caching done -> safe to kill Dh/Dl alias
  // re-zero Y region (y0 = 0)
  {
    unsigned int* z = (unsigned int*)smc;
    for (int i = tid; i < (OFF_DTH) / 2; i += 512) z[i] = 0u;
  }
  __syncthreads();

  float tk = 1.0f;

  for (int it = 0; it < NITER; ++it) {
    // ---- phase A
    if (wave < 6) {
      floatx4 a0 = {0.f, 0.f, 0.f, 0.f}, a1 = {0.f, 0.f, 0.f, 0.f};
      const int n0 = 16 * ntA + ln, n1 = n0 + 16;
      #pragma unroll
      for (int ks = 0; ks < NKA; ++ks) {
        const int ko = 32 * ks + 8 * q;
        const half8 bh0 = *(const half8*)(Yh + n0 * PKS + ko);
        const half8 bl0 = *(const half8*)(Yl + n0 * PKS + ko);
        const half8 bh1 = *(const half8*)(Yh + n1 * PKS + ko);
        const half8 bl1 = *(const half8*)(Yl + n1 * PKS + ko);
        a0 = __builtin_amdgcn_mfma_f32_16x16x32_f16(DhF[ks], bh0, a0, 0, 0, 0);
        a0 = __builtin_amdgcn_mfma_f32_16x16x32_f16(DhF[ks], bl0, a0, 0, 0, 0);
        a0 = __builtin_amdgcn_mfma_f32_16x16x32_f16(DlF[ks], bh0, a0, 0, 0, 0);
        a1 = __builtin_amdgcn_mfma_f32_16x16x32_f16(DhF[ks], bh1, a1, 0, 0, 0);
        a1 = __builtin_amdgcn_mfma_f32_16x16x32_f16(DhF[ks], bl1, a1, 0, 0, 0);
        a1 = __builtin_amdgcn_mfma_f32_16x16x32_f16(DlF[ks], bh1, a1, 0, 0, 0);
      }
      const int t0 = 16 * mtA + 4 * q;
      #pragma unroll
      for (int j = 0; j < 2; ++j) {
        const int c = 16 * (ntA + j) + ln;
        half4 hv, lv;
        #pragma unroll
        for (int r = 0; r < 4; ++r) {
          const float f = yA[j][r] - (j ? a1[r] : a0[r]);
          const half_t h = (half_t)f;
          hv[r] = h;
          lv[r] = (half_t)(f - (float)h);
        }
        *(half4*)(Rh + c * TKS + t0) = hv;
        *(half4*)(Rl + c * TKS + t0) = lv;
      }
    }
    __syncthreads();

    const float tnew = 0.5f * (1.0f + sqrtf(1.0f + 4.0f * tk * tk));
    const float ttf = (tk - 1.0f) / tnew;
    tk = tnew;

    // ---- phase B
    {
      floatx4 acc[3][2];
      #pragma unroll
      for (int ti = 0; ti < 3; ++ti) {
        acc[ti][0] = (floatx4){0.f, 0.f, 0.f, 0.f};
        acc[ti][1] = (floatx4){0.f, 0.f, 0.f, 0.f};
      }
      const int n1 = nB0 + 16;
      #pragma unroll
      for (int ks = 0; ks < NKB; ++ks) {
        const int ko = 32 * ks + 8 * q;
        const half8 bh0 = *(const half8*)(Rh + nB0 * TKS + ko);
        const half8 bl0 = *(const half8*)(Rl + nB0 * TKS + ko);
        const half8 bh1 = *(const half8*)(Rh + n1 * TKS + ko);
        const half8 bl1 = *(const half8*)(Rl + n1 * TKS + ko);
        #pragma unroll
        for (int ti = 0; ti < 3; ++ti) {
          if (ti < nTB) {
            acc[ti][0] = __builtin_amdgcn_mfma_f32_16x16x32_f16(DtHF[ti][ks], bh0, acc[ti][0], 0, 0, 0);
            acc[ti][0] = __builtin_amdgcn_mfma_f32_16x16x32_f16(DtHF[ti][ks], bl0, acc[ti][0], 0, 0, 0);
            acc[ti][0] = __builtin_amdgcn_mfma_f32_16x16x32_f16(DtLF[ti][ks], bh0, acc[ti][0], 0, 0, 0);
            acc[ti][1] = __builtin_amdgcn_mfma_f32_16x16x32_f16(DtHF[ti][ks], bh1, acc[ti][1], 0, 0, 0);
            acc[ti][1] = __builtin_amdgcn_mfma_f32_16x16x32_f16(DtHF[ti][ks], bl1, acc[ti][1], 0, 0, 0);
            acc[ti][1] = __builtin_amdgcn_mfma_f32_16x16x32_f16(DtLF[ti][ks], bh1, acc[ti][1], 0, 0, 0);
          }
        }
      }
      #pragma unroll
      for (int ti = 0; ti < 3; ++ti) {
        if (ti < nTB) {
          const int p0 = 16 * (gB + 4 * ti) + 4 * q;
          #pragma unroll
          for (int j = 0; j < 2; ++j) {
            const int c = nB0 + 16 * j;
            half4 hv, lv;
            #pragma unroll
            for (int r = 0; r < 4; ++r) {
              const float w = yR[ti][j][r] + L_inv * acc[ti][j][r];
              float a = fabsf(w) - thr;
              a = a > 0.0f ? a : 0.0f;
              const float xn = copysignf(a, w);
              const float yn = (1.0f + ttf) * xn - ttf * xR[ti][j][r];
              xR[ti][j][r] = xn;
              yR[ti][j][r] = yn;
              const half_t h = (half_t)yn;
              hv[r] = h;
              lv[r] = (half_t)(yn - (float)h);
            }
            *(half4*)(Yh + c * PKS + p0) = hv;
            *(half4*)(Yl + c * PKS + p0) = lv;
          }
        }
      }
    }
    __syncthreads();
  }

  // ---- outputs: C = x_fin
  float* Cb = outC + b * PDIM * NCOL;
  #pragma unroll
  for (int ti = 0; ti < 3; ++ti) {
    if (ti < nTB) {
      #pragma unroll
      for (int j = 0; j < 2; ++j) {
        const int c = nB0 + 16 * j;
        #pragma unroll
        for (int r = 0; r < 4; ++r) {
          const int p = 16 * (gB + 4 * ti) + 4 * q + r;
          if (p < PDIM && c < NCOL) Cb[p * NCOL + c] = xR[ti][j][r];
        }
      }
    }
  }

  // ---- reconst = D @ C : put x hi/lo into Y arrays, rerun phase-A GEMM
  #pragma unroll
  for (int ti = 0; ti < 3; ++ti) {
    if (ti < nTB) {
      const int p0 = 16 * (gB + 4 * ti) + 4 * q;
      #pragma unroll
      for (int j = 0; j < 2; ++j) {
        const int c = nB0 + 16 * j;
        half4 hv, lv;
        #pragma unroll
        for (int r = 0; r < 4; ++r) {
          const float v = xR[ti][j][r];
          const half_t h = (half_t)v;
          hv[r] = h;
          lv[r] = (half_t)(v - (float)h);
        }
        *(half4*)(Yh + c * PKS + p0) = hv;
        *(half4*)(Yl + c * PKS + p0) = lv;
      }
    }
  }
  __syncthreads();
  if (wave < 6) {
    floatx4 a0 = {0.f, 0.f, 0.f, 0.f}, a1 = {0.f, 0.f, 0.f, 0.f};
    const int n0 = 16 * ntA + ln, n1 = n0 + 16;
    #pragma unroll
    for (int ks = 0; ks < NKA; ++ks) {
      const int ko = 32 * ks + 8 * q;
      const half8 bh0 = *(const half8*)(Yh + n0 * PKS + ko);
      const half8 bl0 = *(const half8*)(Yl + n0 * PKS + ko);
      const half8 bh1 = *(const half8*)(Yh + n1 * PKS + ko);
      const half8 bl1 = *(const half8*)(Yl + n1 * PKS + ko);
      a0 = __builtin_amdgcn_mfma_f32_16x16x32_f16(DhF[ks], bh0, a0, 0, 0, 0);
      a0 = __builtin_amdgcn_mfma_f32_16x16x32_f16(DhF[ks], bl0, a0, 0, 0, 0);
      a0 = __builtin_amdgcn_mfma_f32_16x16x32_f16(DlF[ks], bh0, a0, 0, 0, 0);
      a1 = __builtin_amdgcn_mfma_f32_16x16x32_f16(DhF[ks], bh1, a1, 0, 0, 0);
      a1 = __builtin_amdgcn_mfma_f32_16x16x32_f16(DhF[ks], bl1, a1, 0, 0, 0);
      a1 = __builtin_amdgcn_mfma_f32_16x16x32_f16(DlF[ks], bh1, a1, 0, 0, 0);
    }
    float* Rb = outR + b * TDIM * NCOL;
    const int t0 = 16 * mtA + 4 * q;
    #pragma unroll
    for (int j = 0; j < 2; ++j) {
      const int c = 16 * (ntA + j) + ln;
      if (c < NCOL) {
        #pragma unroll
        for (int r = 0; r < 4; ++r) {
          const int t = t0 + r;
          if (t < TDIM) Rb[t * NCOL + c] = (j ? a1[r] : a0[r]);
        }
      }
    }
  }
}

// ---------------- launch --------------------------------------------------------------

extern "C" void kernel_launch(void* const* d_in, const int* in_sizes, int n_in,
                              void* d_out, int out_size, void* d_ws, size_t ws_size,
                              hipStream_t stream) {
  const float* x     = (const float*)d_in[0];   // (256, 36, 50)
  const float* rho   = (const float*)d_in[1];   // (80,)
  const float* theta = (const float*)d_in[2];   // (80,)

  float* out    = (float*)d_out;
  float* outC   = out;                              // 256*161*50
  float* outDic = out + 256 * PDIM * NCOL;          // 36*161
  float* outR   = outDic + TDIM * PDIM;             // 256*36*50

  float* wsD = (float*)d_ws;                        // normalized dictionary
  float* wsS = wsD + TDIM * PDIM;                   // [L_inv, thr]

  hipLaunchKernelGGL(setup_kernel, dim3(1), dim3(256), 0, stream,
                     rho, theta, wsD, wsS, outDic);

  const size_t smem = (size_t)LDS_FP16_TOTAL * sizeof(half_t);  // 120,320 B
  hipLaunchKernelGGL(fista_kernel, dim3(256), dim3(512), smem, stream,
                     x, wsD, wsS, outC, outR);
}

// Round 4
// 366.417 us; speedup vs baseline: 11.2533x; 1.1765x over previous
//
#include <hip/hip_runtime.h>
#include <math.h>

typedef _Float16 half_t;
typedef __attribute__((ext_vector_type(8))) _Float16 half8;
typedef __attribute__((ext_vector_type(4))) _Float16 half4;
typedef __attribute__((ext_vector_type(4))) float floatx4;

#define TDIM 36
#define PDIM 161        // 2*80+1 atoms
#define NCOL 50
#define NITER 100
#define PITER2 200      // power steps on G^2  == 400 steps on G (R3-equivalent)

// fista LDS geometry (fp16 units). K_A = p padded to 192; K_B = t padded to 64.
#define PKS 200   // p-contiguous row stride (100 dw)
#define TKS 72    // t-contiguous row stride (36 dw)
#define NKA 6
#define NKB 2

// fp16-unit offsets
#define OFF_YH  0                       // [64][PKS]  y^T hi   (B operand, phase A)
#define OFF_YL  12800                   // [64][PKS]  y^T lo
#define OFF_DTH 25600                   // [176][TKS] D^T hi   (A operand, phase B)
#define OFF_DTL 38272                   // [176][TKS] D^T lo
#define OFF_RH  50944                   // [64][TKS]  R^T hi   (B operand, phase B)
#define OFF_RL  55552                   // [64][TKS]  R^T lo
#define OFF_SC  60160                   // 2 floats: L_inv, thr
#define LDS_FP16_TOTAL 60168            // 120,336 bytes

// setup aliases (float units). Df/Gs overlay the Y region (bytes [0,51200));
// G2 overlays the Rh/Rl region (bytes [101888,120320)). All re-zeroed before loop.
#define SPS 196                          // Df row stride (49 quads, odd -> banks spread)
#define OFF_DF32 0                       // [48][SPS] floats = 37,632 B
#define OFF_GS   9408                    // [64][44]  floats = 11,264 B (end 48,896 B)
#define GSTR 44

__global__ __launch_bounds__(512)
void dan_kernel(const float* __restrict__ xin, const float* __restrict__ rho,
                const float* __restrict__ theta, float* __restrict__ outC,
                float* __restrict__ outDic, float* __restrict__ outR)
{
  extern __shared__ char smc[];
  half_t* sh  = (half_t*)smc;
  half_t* Yh  = sh + OFF_YH;
  half_t* Yl  = sh + OFF_YL;
  half_t* Dth = sh + OFF_DTH;
  half_t* Dtl = sh + OFF_DTL;
  half_t* Rh  = sh + OFF_RH;
  half_t* Rl  = sh + OFF_RL;
  float*  Df  = (float*)smc + OFF_DF32;  // setup alias
  float*  Gs  = (float*)smc + OFF_GS;    // setup alias
  float*  G2  = (float*)(sh + OFF_RH);   // setup alias
  float*  sc  = (float*)(sh + OFF_SC);

  const int tid = threadIdx.x;
  const int b = blockIdx.x;
  const int wave = tid >> 6, lane = tid & 63;
  const int q = lane >> 4, ln = lane & 15;

  // ---- A. zero all LDS (pads must be 0)
  {
    unsigned int* z = (unsigned int*)smc;
    for (int i = tid; i < LDS_FP16_TOTAL / 2; i += 512) z[i] = 0u;
  }
  __syncthreads();

  // ---- B. build normalized dictionary in fp32 (one column per thread)
  if (tid < PDIM) {
    if (tid == 0) {
      for (int t = 0; t < TDIM; ++t) Df[t * SPS] = 1.0f;
    } else {
      const bool is_sin = tid > 80;
      const int n = is_sin ? (tid - 81) : (tid - 1);
      const float rr = 0.001f + 1.149f / (1.0f + expf(-rho[n]));
      const float th = 3.14159265358979f / (1.0f + expf(-theta[n]));
      const float lr = logf(rr);
      float s2 = 0.0f;
      for (int t = 0; t < TDIM; ++t) {
        const float ft = (float)t;
        const float val = expf(ft * lr) * (is_sin ? sinf(ft * th) : cosf(ft * th));
        Df[t * SPS + tid] = val;
        s2 += val * val;
      }
      const float inv = 1.0f / sqrtf(s2);
      for (int t = 0; t < TDIM; ++t) Df[t * SPS + tid] *= inv;
    }
  }
  __syncthreads();

  // ---- C. Gram G = D D^T (upper triangle + mirror) ; stage D^T fp16 ; dic out
  for (int job = tid; job < 666; job += 512) {         // 666 = 36*37/2
    int i = 0, rem = job;
    while (rem >= TDIM - i) { rem -= TDIM - i; ++i; }
    const int j = i + rem;
    const float4* ri = (const float4*)(Df + i * SPS);
    const float4* rj = (const float4*)(Df + j * SPS);
    float a = 0.0f;
    #pragma unroll 7
    for (int k = 0; k < SPS / 4; ++k) {
      const float4 x = ri[k], y = rj[k];
      a += x.x * y.x + x.y * y.y + x.z * y.z + x.w * y.w;
    }
    Gs[i * GSTR + j] = a;
    Gs[j * GSTR + i] = a;
  }
  for (int i = tid; i < TDIM * PDIM; i += 512) {
    const int t = i / PDIM, p = i - t * PDIM;
    const float v = Df[t * SPS + p];
    const half_t h = (half_t)v;
    Dth[p * TKS + t] = h;
    Dtl[p * TKS + t] = (half_t)(v - (float)h);
    if (b == 0) outDic[i] = v;
  }
  __syncthreads();

  // ---- C2. G2 = G*G (rows 36..63 of Gs are zero; cols 36..43 zero)
  for (int job = tid; job < 666; job += 512) {
    int i = 0, rem = job;
    while (rem >= TDIM - i) { rem -= TDIM - i; ++i; }
    const int j = i + rem;
    const float4* ri = (const float4*)(Gs + i * GSTR);
    const float4* rj = (const float4*)(Gs + j * GSTR);
    float a = 0.0f;
    #pragma unroll
    for (int k = 0; k < GSTR / 4; ++k) {
      const float4 x = ri[k], y = rj[k];
      a += x.x * y.x + x.y * y.y + x.z * y.z + x.w * y.w;
    }
    G2[i * GSTR + j] = a;
    G2[j * GSTR + i] = a;
  }
  __syncthreads();

  // ---- D. ownership (R3 maps, unchanged)
  const int mtA = wave >> 1;                 // phase A: waves 0..5, m-tile, 2 n-tiles
  const int ntA = (wave & 1) * 2;
  const int gB = wave >> 1;                  // phase B: all 8 waves
  const int nTB = (gB == 3) ? 2 : 3;
  const int nB0 = 32 * (wave & 1) + ln;

  // phase-A A-fragments straight from fp32 D (rows >=36 are zero)
  half8 DhF[NKA], DlF[NKA];
  if (wave < 6) {
    const int row = 16 * mtA + ln;
    #pragma unroll
    for (int ks = 0; ks < NKA; ++ks) {
      const float4 f0 = *(const float4*)(Df + row * SPS + 32 * ks + 8 * q);
      const float4 f1 = *(const float4*)(Df + row * SPS + 32 * ks + 8 * q + 4);
      const float fa[8] = {f0.x, f0.y, f0.z, f0.w, f1.x, f1.y, f1.z, f1.w};
      half8 hh, ll;
      #pragma unroll
      for (int e = 0; e < 8; ++e) {
        const half_t h = (half_t)fa[e];
        hh[e] = h;
        ll[e] = (half_t)(fa[e] - (float)h);
      }
      DhF[ks] = hh;
      DlF[ks] = ll;
    }
  }
  // phase-B A-fragments from staged fp16 D^T
  half8 DtHF[3][NKB], DtLF[3][NKB];
  #pragma unroll
  for (int ti = 0; ti < 3; ++ti) {
    if (ti < nTB) {
      const int row = 16 * (gB + 4 * ti) + ln;
      #pragma unroll
      for (int ks = 0; ks < NKB; ++ks) {
        DtHF[ti][ks] = *(const half8*)(Dth + row * TKS + 32 * ks + 8 * q);
        DtLF[ti][ks] = *(const half8*)(Dtl + row * TKS + 32 * ks + 8 * q);
      }
    }
  }
  // static Y (fp32) at phase-A C positions
  float yA[2][4];
  if (wave < 6) {
    const float* xb = xin + b * TDIM * NCOL;
    #pragma unroll
    for (int j = 0; j < 2; ++j) {
      const int c = 16 * (ntA + j) + ln;
      #pragma unroll
      for (int r = 0; r < 4; ++r) {
        const int t = 16 * mtA + 4 * q + r;
        yA[j][r] = (t < TDIM && c < NCOL) ? xb[t * NCOL + c] : 0.0f;
      }
    }
  }

  // ---- D2. wave 0: power iteration on G2 (VALU readlane broadcasts, no barriers)
  if (wave == 0) {
    float g2r[36];
    #pragma unroll
    for (int j = 0; j < 36; ++j) g2r[j] = G2[lane * GSTR + j];  // rows>=36 zero
    float v = (lane < 36) ? 1.0f : 0.0f;
    for (int it = 0; it < PITER2; ++it) {
      const int vi = __float_as_int(v);
      float w0 = 0.0f, w1 = 0.0f;
      #pragma unroll
      for (int j = 0; j < 36; j += 2) {
        w0 = fmaf(g2r[j],     __int_as_float(__builtin_amdgcn_readlane(vi, j)),     w0);
        w1 = fmaf(g2r[j + 1], __int_as_float(__builtin_amdgcn_readlane(vi, j + 1)), w1);
      }
      float w = w0 + w1;
      if ((it & 3) == 3) {                 // lam(G2)^4 <= (196^2)^4 ~ 2e18: safe
        float s = w * w;
        #pragma unroll
        for (int off = 32; off > 0; off >>= 1) s += __shfl_xor(s, off, 64);
        w *= rsqrtf(s);
      }
      v = w;
    }
    // v is unit (it=199 renormalized). Rayleigh on ORIGINAL G: lam = v.Gv
    const int vi = __float_as_int(v);
    float w0 = 0.0f, w1 = 0.0f;
    #pragma unroll
    for (int j = 0; j < 36; j += 2) {
      w0 = fmaf(Gs[lane * GSTR + j],     __int_as_float(__builtin_amdgcn_readlane(vi, j)),     w0);
      w1 = fmaf(Gs[lane * GSTR + j + 1], __int_as_float(__builtin_amdgcn_readlane(vi, j + 1)), w1);
    }
    float num = v * (w0 + w1);
    #pragma unroll
    for (int off = 32; off > 0; off >>= 1) num += __shfl_xor(num, off, 64);
    if (lane == 0) {
      sc[0] = 1.0f / num;        // L_inv
      sc[1] = 0.1f / num;        // thr = lam_f * L_inv
    }
  }
  __syncthreads();

  // ---- E. kill aliases: zero Y region and Rh/Rl region; read scalars
  {
    unsigned int* z = (unsigned int*)smc;
    for (int i = tid; i < OFF_DTH / 2; i += 512) z[i] = 0u;
    for (int i = OFF_RH / 2 + tid; i < OFF_SC / 2; i += 512) z[i] = 0u;
  }
  __syncthreads();
  const float L_inv = sc[0];
  const float thr = sc[1];

  float xR[3][2][4], yR[3][2][4];
  #pragma unroll
  for (int ti = 0; ti < 3; ++ti)
    #pragma unroll
    for (int j = 0; j < 2; ++j)
      #pragma unroll
      for (int r = 0; r < 4; ++r) { xR[ti][j][r] = 0.0f; yR[ti][j][r] = 0.0f; }

  float tk = 1.0f;

  // ---- F. FISTA loop (R3 structure, proven)
  for (int it = 0; it < NITER; ++it) {
    // phase A: R = Y - D y   (M=48, N=64, K=192)
    if (wave < 6) {
      floatx4 a0 = {0.f, 0.f, 0.f, 0.f}, a1 = {0.f, 0.f, 0.f, 0.f};
      const int n0 = 16 * ntA + ln, n1 = n0 + 16;
      #pragma unroll
      for (int ks = 0; ks < NKA; ++ks) {
        const int ko = 32 * ks + 8 * q;
        const half8 bh0 = *(const half8*)(Yh + n0 * PKS + ko);
        const half8 bl0 = *(const half8*)(Yl + n0 * PKS + ko);
        const half8 bh1 = *(const half8*)(Yh + n1 * PKS + ko);
        const half8 bl1 = *(const half8*)(Yl + n1 * PKS + ko);
        a0 = __builtin_amdgcn_mfma_f32_16x16x32_f16(DhF[ks], bh0, a0, 0, 0, 0);
        a0 = __builtin_amdgcn_mfma_f32_16x16x32_f16(DhF[ks], bl0, a0, 0, 0, 0);
        a0 = __builtin_amdgcn_mfma_f32_16x16x32_f16(DlF[ks], bh0, a0, 0, 0, 0);
        a1 = __builtin_amdgcn_mfma_f32_16x16x32_f16(DhF[ks], bh1, a1, 0, 0, 0);
        a1 = __builtin_amdgcn_mfma_f32_16x16x32_f16(DhF[ks], bl1, a1, 0, 0, 0);
        a1 = __builtin_amdgcn_mfma_f32_16x16x32_f16(DlF[ks], bh1, a1, 0, 0, 0);
      }
      const int t0 = 16 * mtA + 4 * q;
      #pragma unroll
      for (int j = 0; j < 2; ++j) {
        const int c = 16 * (ntA + j) + ln;
        half4 hv, lv;
        #pragma unroll
        for (int r = 0; r < 4; ++r) {
          const float f = yA[j][r] - (j ? a1[r] : a0[r]);
          const half_t h = (half_t)f;
          hv[r] = h;
          lv[r] = (half_t)(f - (float)h);
        }
        *(half4*)(Rh + c * TKS + t0) = hv;
        *(half4*)(Rl + c * TKS + t0) = lv;
      }
    }
    __syncthreads();

    const float tnew = 0.5f * (1.0f + sqrtf(1.0f + 4.0f * tk * tk));
    const float ttf = (tk - 1.0f) / tnew;
    tk = tnew;

    // phase B: w = y + L_inv D^T R ; shrink + momentum  (M=176, N=64, K=64)
    {
      floatx4 acc[3][2];
      #pragma unroll
      for (int ti = 0; ti < 3; ++ti) {
        acc[ti][0] = (floatx4){0.f, 0.f, 0.f, 0.f};
        acc[ti][1] = (floatx4){0.f, 0.f, 0.f, 0.f};
      }
      const int n1 = nB0 + 16;
      #pragma unroll
      for (int ks = 0; ks < NKB; ++ks) {
        const int ko = 32 * ks + 8 * q;
        const half8 bh0 = *(const half8*)(Rh + nB0 * TKS + ko);
        const half8 bl0 = *(const half8*)(Rl + nB0 * TKS + ko);
        const half8 bh1 = *(const half8*)(Rh + n1 * TKS + ko);
        const half8 bl1 = *(const half8*)(Rl + n1 * TKS + ko);
        #pragma unroll
        for (int ti = 0; ti < 3; ++ti) {
          if (ti < nTB) {
            acc[ti][0] = __builtin_amdgcn_mfma_f32_16x16x32_f16(DtHF[ti][ks], bh0, acc[ti][0], 0, 0, 0);
            acc[ti][0] = __builtin_amdgcn_mfma_f32_16x16x32_f16(DtHF[ti][ks], bl0, acc[ti][0], 0, 0, 0);
            acc[ti][0] = __builtin_amdgcn_mfma_f32_16x16x32_f16(DtLF[ti][ks], bh0, acc[ti][0], 0, 0, 0);
            acc[ti][1] = __builtin_amdgcn_mfma_f32_16x16x32_f16(DtHF[ti][ks], bh1, acc[ti][1], 0, 0, 0);
            acc[ti][1] = __builtin_amdgcn_mfma_f32_16x16x32_f16(DtHF[ti][ks], bl1, acc[ti][1], 0, 0, 0);
            acc[ti][1] = __builtin_amdgcn_mfma_f32_16x16x32_f16(DtLF[ti][ks], bh1, acc[ti][1], 0, 0, 0);
          }
        }
      }
      #pragma unroll
      for (int ti = 0; ti < 3; ++ti) {
        if (ti < nTB) {
          const int p0 = 16 * (gB + 4 * ti) + 4 * q;
          #pragma unroll
          for (int j = 0; j < 2; ++j) {
            const int c = nB0 + 16 * j;
            half4 hv, lv;
            #pragma unroll
            for (int r = 0; r < 4; ++r) {
              const float w = yR[ti][j][r] + L_inv * acc[ti][j][r];
              float a = fabsf(w) - thr;
              a = a > 0.0f ? a : 0.0f;
              const float xn = copysignf(a, w);
              const float yn = (1.0f + ttf) * xn - ttf * xR[ti][j][r];
              xR[ti][j][r] = xn;
              yR[ti][j][r] = yn;
              const half_t h = (half_t)yn;
              hv[r] = h;
              lv[r] = (half_t)(yn - (float)h);
            }
            *(half4*)(Yh + c * PKS + p0) = hv;
            *(half4*)(Yl + c * PKS + p0) = lv;
          }
        }
      }
    }
    __syncthreads();
  }

  // ---- G. outputs: C = x_fin
  float* Cb = outC + b * PDIM * NCOL;
  #pragma unroll
  for (int ti = 0; ti < 3; ++ti) {
    if (ti < nTB) {
      #pragma unroll
      for (int j = 0; j < 2; ++j) {
        const int c = nB0 + 16 * j;
        #pragma unroll
        for (int r = 0; r < 4; ++r) {
          const int p = 16 * (gB + 4 * ti) + 4 * q + r;
          if (p < PDIM && c < NCOL) Cb[p * NCOL + c] = xR[ti][j][r];
        }
      }
    }
  }
  // reconst = D @ C : stage x hi/lo into Y arrays, rerun phase-A GEMM
  #pragma unroll
  for (int ti = 0; ti < 3; ++ti) {
    if (ti < nTB) {
      const int p0 = 16 * (gB + 4 * ti) + 4 * q;
      #pragma unroll
      for (int j = 0; j < 2; ++j) {
        const int c = nB0 + 16 * j;
        half4 hv, lv;
        #pragma unroll
        for (int r = 0; r < 4; ++r) {
          const float v = xR[ti][j][r];
          const half_t h = (half_t)v;
          hv[r] = h;
          lv[r] = (half_t)(v - (float)h);
        }
        *(half4*)(Yh + c * PKS + p0) = hv;
        *(half4*)(Yl + c * PKS + p0) = lv;
      }
    }
  }
  __syncthreads();
  if (wave < 6) {
    floatx4 a0 = {0.f, 0.f, 0.f, 0.f}, a1 = {0.f, 0.f, 0.f, 0.f};
    const int n0 = 16 * ntA + ln, n1 = n0 + 16;
    #pragma unroll
    for (int ks = 0; ks < NKA; ++ks) {
      const int ko = 32 * ks + 8 * q;
      const half8 bh0 = *(const half8*)(Yh + n0 * PKS + ko);
      const half8 bl0 = *(const half8*)(Yl + n0 * PKS + ko);
      const half8 bh1 = *(const half8*)(Yh + n1 * PKS + ko);
      const half8 bl1 = *(const half8*)(Yl + n1 * PKS + ko);
      a0 = __builtin_amdgcn_mfma_f32_16x16x32_f16(DhF[ks], bh0, a0, 0, 0, 0);
      a0 = __builtin_amdgcn_mfma_f32_16x16x32_f16(DhF[ks], bl0, a0, 0, 0, 0);
      a0 = __builtin_amdgcn_mfma_f32_16x16x32_f16(DlF[ks], bh0, a0, 0, 0, 0);
      a1 = __builtin_amdgcn_mfma_f32_16x16x32_f16(DhF[ks], bh1, a1, 0, 0, 0);
      a1 = __builtin_amdgcn_mfma_f32_16x16x32_f16(DhF[ks], bl1, a1, 0, 0, 0);
      a1 = __builtin_amdgcn_mfma_f32_16x16x32_f16(DlF[ks], bh1, a1, 0, 0, 0);
    }
    float* Rb = outR + b * TDIM * NCOL;
    const int t0 = 16 * mtA + 4 * q;
    #pragma unroll
    for (int j = 0; j < 2; ++j) {
      const int c = 16 * (ntA + j) + ln;
      if (c < NCOL) {
        #pragma unroll
        for (int r = 0; r < 4; ++r) {
          const int t = t0 + r;
          if (t < TDIM) Rb[t * NCOL + c] = (j ? a1[r] : a0[r]);
        }
      }
    }
  }
}

// ---------------- launch --------------------------------------------------------------

extern "C" void kernel_launch(void* const* d_in, const int* in_sizes, int n_in,
                              void* d_out, int out_size, void* d_ws, size_t ws_size,
                              hipStream_t stream) {
  const float* x     = (const float*)d_in[0];   // (256, 36, 50)
  const float* rho   = (const float*)d_in[1];   // (80,)
  const float* theta = (const float*)d_in[2];   // (80,)

  float* out    = (float*)d_out;
  float* outC   = out;                              // 256*161*50
  float* outDic = out + 256 * PDIM * NCOL;          // 36*161
  float* outR   = outDic + TDIM * PDIM;             // 256*36*50

  const size_t smem = (size_t)LDS_FP16_TOTAL * sizeof(half_t);  // 120,336 B
  hipLaunchKernelGGL(dan_kernel, dim3(256), dim3(512), smem, stream,
                     x, rho, theta, outC, outDic, outR);
}

// Round 5
// 279.619 us; speedup vs baseline: 14.7464x; 1.3104x over previous
//
#include <hip/hip_runtime.h>
#include <math.h>

typedef _Float16 half_t;
typedef __attribute__((ext_vector_type(8))) _Float16 half8;
typedef __attribute__((ext_vector_type(4))) _Float16 half4;
typedef __attribute__((ext_vector_type(4))) float floatx4;

#define TDIM 36
#define PDIM 161        // 2*80+1 atoms
#define NCOL 50
#define NITER 100
#define PITER2 200      // power steps on G^2 == 400 on G (proven R3/R4 accuracy)

// GEMM geometry: phase A K = p padded to 192 (6 ks of 32); phase B K = t padded to 64.
#define NKA 6
#define NKB 2
#define YKS 200         // Y row stride (halves): 100 dw, bank-balanced (verified R4 math)
#define RKS 72          // R / Dt row stride (halves): 36 dw
#define SPS 196         // Df (fp32) row stride

// ---- byte-offset LDS map (single fp16 iterate arrays; D keeps hi/lo) ----
#define BY_Y    0                      // [64][YKS] half : y^T      (25,600 B)
#define BY_R    25600                  // [64][RKS] half : R^T      ( 9,216 B)
#define BY_DTH  34816                  // [176][RKS] half: D^T hi   (25,344 B)
#define BY_DTL  60160                  // [176][RKS] half: D^T lo   (25,344 B)
#define BY_SC   85504                  // 2 floats: L_inv, thr
#define BY_GS   85520                  // [36][44] fp32 Gram        ( 6,336 B)
#define BY_G2   91856                  // [36][44] fp32 Gram^2      ( 6,336 B)
#define LDS_TOTAL 98192
// setup-only alias: Df [36][SPS] fp32 = 28,224 B over Y+R region (re-zeroed before loop)
#define GSTR 44

__global__ __launch_bounds__(512)
void dan_kernel(const float* __restrict__ xin, const float* __restrict__ rho,
                const float* __restrict__ theta, float* __restrict__ outC,
                float* __restrict__ outDic, float* __restrict__ outR)
{
  extern __shared__ char smc[];
  half_t* Yv  = (half_t*)(smc + BY_Y);
  half_t* Rv  = (half_t*)(smc + BY_R);
  half_t* Dth = (half_t*)(smc + BY_DTH);
  half_t* Dtl = (half_t*)(smc + BY_DTL);
  float*  sc  = (float*)(smc + BY_SC);
  float*  Gs  = (float*)(smc + BY_GS);
  float*  G2  = (float*)(smc + BY_G2);
  float*  Df  = (float*)(smc + BY_Y);   // setup alias over Y+R

  const int tid = threadIdx.x;
  const int b = blockIdx.x;
  const int wave = tid >> 6, lane = tid & 63;
  const int q = lane >> 4, ln = lane & 15;

  // ---- A. zero all LDS (pads must be 0)
  {
    unsigned int* z = (unsigned int*)smc;
    for (int i = tid; i < LDS_TOTAL / 4; i += 512) z[i] = 0u;
  }
  __syncthreads();

  // ---- B. build normalized dictionary (fp32, one column per thread)
  if (tid < PDIM) {
    if (tid == 0) {
      for (int t = 0; t < TDIM; ++t) Df[t * SPS] = 1.0f;
    } else {
      const bool is_sin = tid > 80;
      const int n = is_sin ? (tid - 81) : (tid - 1);
      const float rr = 0.001f + 1.149f / (1.0f + expf(-rho[n]));
      const float th = 3.14159265358979f / (1.0f + expf(-theta[n]));
      const float lr = logf(rr);
      float s2 = 0.0f;
      for (int t = 0; t < TDIM; ++t) {
        const float ft = (float)t;
        const float val = expf(ft * lr) * (is_sin ? sinf(ft * th) : cosf(ft * th));
        Df[t * SPS + tid] = val;
        s2 += val * val;
      }
      const float inv = 1.0f / sqrtf(s2);
      for (int t = 0; t < TDIM; ++t) Df[t * SPS + tid] *= inv;
    }
  }
  __syncthreads();

  // ---- C. Gram (upper tri + mirror) ; stage D^T hi/lo ; dic out
  for (int job = tid; job < 666; job += 512) {         // 666 = 36*37/2
    int i = 0, rem = job;
    while (rem >= TDIM - i) { rem -= TDIM - i; ++i; }
    const int j = i + rem;
    const float4* ri = (const float4*)(Df + i * SPS);
    const float4* rj = (const float4*)(Df + j * SPS);
    float a = 0.0f;
    #pragma unroll 7
    for (int k = 0; k < SPS / 4; ++k) {
      const float4 x = ri[k], y = rj[k];
      a += x.x * y.x + x.y * y.y + x.z * y.z + x.w * y.w;
    }
    Gs[i * GSTR + j] = a;
    Gs[j * GSTR + i] = a;
  }
  for (int i = tid; i < TDIM * PDIM; i += 512) {
    const int t = i / PDIM, p = i - t * PDIM;
    const float v = Df[t * SPS + p];
    const half_t h = (half_t)v;
    Dth[p * RKS + t] = h;
    Dtl[p * RKS + t] = (half_t)(v - (float)h);
    if (b == 0) outDic[i] = v;
  }
  __syncthreads();

  // ---- C2. G2 = G*G (cols 36..43 of Gs are zero)
  for (int job = tid; job < 666; job += 512) {
    int i = 0, rem = job;
    while (rem >= TDIM - i) { rem -= TDIM - i; ++i; }
    const int j = i + rem;
    const float4* ri = (const float4*)(Gs + i * GSTR);
    const float4* rj = (const float4*)(Gs + j * GSTR);
    float a = 0.0f;
    #pragma unroll
    for (int k = 0; k < GSTR / 4; ++k) {
      const float4 x = ri[k], y = rj[k];
      a += x.x * y.x + x.y * y.y + x.z * y.z + x.w * y.w;
    }
    G2[i * GSTR + j] = a;
    G2[j * GSTR + i] = a;
  }
  __syncthreads();

  // ---- D. ownership (R4 maps)
  const int mtA = wave >> 1;                 // phase A: waves 0..5
  const int ntA = (wave & 1) * 2;
  const int gB = wave >> 1;                  // phase B: all 8 waves
  const int nTB = (gB == 3) ? 2 : 3;
  const int nB0 = 32 * (wave & 1) + ln;

  // phase-A A-fragments (D hi/lo) from fp32 Df; rows >= 36 are zero
  half8 DhF[NKA], DlF[NKA];
  if (wave < 6) {
    const int row = 16 * mtA + ln;
    #pragma unroll
    for (int ks = 0; ks < NKA; ++ks) {
      half8 hh = {0,0,0,0,0,0,0,0}, ll = {0,0,0,0,0,0,0,0};
      if (row < TDIM) {
        const float4 f0 = *(const float4*)(Df + row * SPS + 32 * ks + 8 * q);
        const float4 f1 = *(const float4*)(Df + row * SPS + 32 * ks + 8 * q + 4);
        const float fa[8] = {f0.x, f0.y, f0.z, f0.w, f1.x, f1.y, f1.z, f1.w};
        #pragma unroll
        for (int e = 0; e < 8; ++e) {
          const half_t h = (half_t)fa[e];
          hh[e] = h;
          ll[e] = (half_t)(fa[e] - (float)h);
        }
      }
      DhF[ks] = hh;
      DlF[ks] = ll;
    }
  }
  // phase-B A-fragments (D^T hi/lo) from staged fp16
  half8 DtHF[3][NKB], DtLF[3][NKB];
  #pragma unroll
  for (int ti = 0; ti < 3; ++ti) {
    if (ti < nTB) {
      const int row = 16 * (gB + 4 * ti) + ln;
      #pragma unroll
      for (int ks = 0; ks < NKB; ++ks) {
        DtHF[ti][ks] = *(const half8*)(Dth + row * RKS + 32 * ks + 8 * q);
        DtLF[ti][ks] = *(const half8*)(Dtl + row * RKS + 32 * ks + 8 * q);
      }
    }
  }
  // static Y (fp32) at phase-A C positions
  float yA[2][4];
  if (wave < 6) {
    const float* xb = xin + b * TDIM * NCOL;
    #pragma unroll
    for (int j = 0; j < 2; ++j) {
      const int c = 16 * (ntA + j) + ln;
      #pragma unroll
      for (int r = 0; r < 4; ++r) {
        const int t = 16 * mtA + 4 * q + r;
        yA[j][r] = (t < TDIM && c < NCOL) ? xb[t * NCOL + c] : 0.0f;
      }
    }
  }

  // ---- D2. wave 0: power iteration on G2 (readlane broadcasts, no barriers)
  if (wave == 0) {
    float g2r[36];
    #pragma unroll
    for (int j = 0; j < 36; ++j) g2r[j] = (lane < 36) ? G2[lane * GSTR + j] : 0.0f;
    float v = (lane < 36) ? 1.0f : 0.0f;
    for (int it = 0; it < PITER2; ++it) {
      const int vi = __float_as_int(v);
      float w0 = 0.0f, w1 = 0.0f;
      #pragma unroll
      for (int j = 0; j < 36; j += 2) {
        w0 = fmaf(g2r[j],     __int_as_float(__builtin_amdgcn_readlane(vi, j)),     w0);
        w1 = fmaf(g2r[j + 1], __int_as_float(__builtin_amdgcn_readlane(vi, j + 1)), w1);
      }
      float w = w0 + w1;
      if ((it & 3) == 3) {
        float s = w * w;
        #pragma unroll
        for (int off = 32; off > 0; off >>= 1) s += __shfl_xor(s, off, 64);
        w *= rsqrtf(s);
      }
      v = w;
    }
    // Rayleigh on ORIGINAL G (v unit from it=199 renorm)
    const int vi = __float_as_int(v);
    float w0 = 0.0f, w1 = 0.0f;
    #pragma unroll
    for (int j = 0; j < 36; j += 2) {
      const float gi0 = (lane < 36) ? Gs[lane * GSTR + j]     : 0.0f;
      const float gi1 = (lane < 36) ? Gs[lane * GSTR + j + 1] : 0.0f;
      w0 = fmaf(gi0, __int_as_float(__builtin_amdgcn_readlane(vi, j)),     w0);
      w1 = fmaf(gi1, __int_as_float(__builtin_amdgcn_readlane(vi, j + 1)), w1);
    }
    float num = v * (w0 + w1);
    #pragma unroll
    for (int off = 32; off > 0; off >>= 1) num += __shfl_xor(num, off, 64);
    if (lane == 0) {
      sc[0] = 1.0f / num;        // L_inv
      sc[1] = 0.1f / num;        // thr = lam_f * L_inv
    }
  }
  __syncthreads();

  // ---- E. kill Df alias: zero Y+R regions (y0 = 0, pads = 0)
  {
    unsigned int* z = (unsigned int*)smc;
    for (int i = tid; i < (BY_DTH) / 4; i += 512) z[i] = 0u;
  }
  __syncthreads();
  const float L_inv = sc[0];
  const float thr = sc[1];

  float xR[3][2][4], yR[3][2][4];
  #pragma unroll
  for (int ti = 0; ti < 3; ++ti)
    #pragma unroll
    for (int j = 0; j < 2; ++j)
      #pragma unroll
      for (int r = 0; r < 4; ++r) { xR[ti][j][r] = 0.0f; yR[ti][j][r] = 0.0f; }

  float tk = 1.0f;

  // ---- F. FISTA loop: single-fp16 iterates, D in hi/lo (2 MFMA per operand pair)
  for (int it = 0; it < NITER; ++it) {
    // phase A: R = Y - D y   (M=48, N=64, K=192)
    if (wave < 6) {
      floatx4 a0 = {0.f, 0.f, 0.f, 0.f}, a1 = {0.f, 0.f, 0.f, 0.f};
      const int n0 = 16 * ntA + ln, n1 = n0 + 16;
      #pragma unroll
      for (int ks = 0; ks < NKA; ++ks) {
        const int ko = 32 * ks + 8 * q;
        const half8 b0 = *(const half8*)(Yv + n0 * YKS + ko);
        const half8 b1 = *(const half8*)(Yv + n1 * YKS + ko);
        a0 = __builtin_amdgcn_mfma_f32_16x16x32_f16(DhF[ks], b0, a0, 0, 0, 0);
        a0 = __builtin_amdgcn_mfma_f32_16x16x32_f16(DlF[ks], b0, a0, 0, 0, 0);
        a1 = __builtin_amdgcn_mfma_f32_16x16x32_f16(DhF[ks], b1, a1, 0, 0, 0);
        a1 = __builtin_amdgcn_mfma_f32_16x16x32_f16(DlF[ks], b1, a1, 0, 0, 0);
      }
      const int t0 = 16 * mtA + 4 * q;
      #pragma unroll
      for (int j = 0; j < 2; ++j) {
        const int c = 16 * (ntA + j) + ln;
        half4 hv;
        #pragma unroll
        for (int r = 0; r < 4; ++r)
          hv[r] = (half_t)(yA[j][r] - (j ? a1[r] : a0[r]));
        *(half4*)(Rv + c * RKS + t0) = hv;
      }
    }
    __syncthreads();

    const float tnew = 0.5f * (1.0f + sqrtf(1.0f + 4.0f * tk * tk));
    const float ttf = (tk - 1.0f) / tnew;
    tk = tnew;

    // phase B: w = y + L_inv D^T R ; shrink + momentum  (M=176, N=64, K=64)
    {
      floatx4 acc[3][2];
      #pragma unroll
      for (int ti = 0; ti < 3; ++ti) {
        acc[ti][0] = (floatx4){0.f, 0.f, 0.f, 0.f};
        acc[ti][1] = (floatx4){0.f, 0.f, 0.f, 0.f};
      }
      const int n1b = nB0 + 16;
      #pragma unroll
      for (int ks = 0; ks < NKB; ++ks) {
        const int ko = 32 * ks + 8 * q;
        const half8 rb0 = *(const half8*)(Rv + nB0 * RKS + ko);
        const half8 rb1 = *(const half8*)(Rv + n1b * RKS + ko);
        #pragma unroll
        for (int ti = 0; ti < 3; ++ti) {
          if (ti < nTB) {
            acc[ti][0] = __builtin_amdgcn_mfma_f32_16x16x32_f16(DtHF[ti][ks], rb0, acc[ti][0], 0, 0, 0);
            acc[ti][0] = __builtin_amdgcn_mfma_f32_16x16x32_f16(DtLF[ti][ks], rb0, acc[ti][0], 0, 0, 0);
            acc[ti][1] = __builtin_amdgcn_mfma_f32_16x16x32_f16(DtHF[ti][ks], rb1, acc[ti][1], 0, 0, 0);
            acc[ti][1] = __builtin_amdgcn_mfma_f32_16x16x32_f16(DtLF[ti][ks], rb1, acc[ti][1], 0, 0, 0);
          }
        }
      }
      #pragma unroll
      for (int ti = 0; ti < 3; ++ti) {
        if (ti < nTB) {
          const int p0 = 16 * (gB + 4 * ti) + 4 * q;
          #pragma unroll
          for (int j = 0; j < 2; ++j) {
            const int c = nB0 + 16 * j;
            half4 hv;
            #pragma unroll
            for (int r = 0; r < 4; ++r) {
              const float w = yR[ti][j][r] + L_inv * acc[ti][j][r];
              const float cl = fminf(fmaxf(w, -thr), thr);   // v_med3 clamp
              const float xn = w - cl;                        // softshrink
              const float yn = xn + ttf * (xn - xR[ti][j][r]);
              xR[ti][j][r] = xn;
              yR[ti][j][r] = yn;
              hv[r] = (half_t)yn;
            }
            *(half4*)(Yv + c * YKS + p0) = hv;
          }
        }
      }
    }
    __syncthreads();
  }

  // ---- G. outputs: C = x_fin
  float* Cb = outC + b * PDIM * NCOL;
  #pragma unroll
  for (int ti = 0; ti < 3; ++ti) {
    if (ti < nTB) {
      #pragma unroll
      for (int j = 0; j < 2; ++j) {
        const int c = nB0 + 16 * j;
        #pragma unroll
        for (int r = 0; r < 4; ++r) {
          const int p = 16 * (gB + 4 * ti) + 4 * q + r;
          if (p < PDIM && c < NCOL) Cb[p * NCOL + c] = xR[ti][j][r];
        }
      }
    }
  }
  // reconst = D @ C : restage x into Y (fp16), rerun phase-A GEMM
  #pragma unroll
  for (int ti = 0; ti < 3; ++ti) {
    if (ti < nTB) {
      const int p0 = 16 * (gB + 4 * ti) + 4 * q;
      #pragma unroll
      for (int j = 0; j < 2; ++j) {
        const int c = nB0 + 16 * j;
        half4 hv;
        #pragma unroll
        for (int r = 0; r < 4; ++r) hv[r] = (half_t)xR[ti][j][r];
        *(half4*)(Yv + c * YKS + p0) = hv;
      }
    }
  }
  __syncthreads();
  if (wave < 6) {
    floatx4 a0 = {0.f, 0.f, 0.f, 0.f}, a1 = {0.f, 0.f, 0.f, 0.f};
    const int n0 = 16 * ntA + ln, n1 = n0 + 16;
    #pragma unroll
    for (int ks = 0; ks < NKA; ++ks) {
      const int ko = 32 * ks + 8 * q;
      const half8 b0 = *(const half8*)(Yv + n0 * YKS + ko);
      const half8 b1 = *(const half8*)(Yv + n1 * YKS + ko);
      a0 = __builtin_amdgcn_mfma_f32_16x16x32_f16(DhF[ks], b0, a0, 0, 0, 0);
      a0 = __builtin_amdgcn_mfma_f32_16x16x32_f16(DlF[ks], b0, a0, 0, 0, 0);
      a1 = __builtin_amdgcn_mfma_f32_16x16x32_f16(DhF[ks], b1, a1, 0, 0, 0);
      a1 = __builtin_amdgcn_mfma_f32_16x16x32_f16(DlF[ks], b1, a1, 0, 0, 0);
    }
    float* Rb = outR + b * TDIM * NCOL;
    const int t0 = 16 * mtA + 4 * q;
    #pragma unroll
    for (int j = 0; j < 2; ++j) {
      const int c = 16 * (ntA + j) + ln;
      if (c < NCOL) {
        #pragma unroll
        for (int r = 0; r < 4; ++r) {
          const int t = t0 + r;
          if (t < TDIM) Rb[t * NCOL + c] = (j ? a1[r] : a0[r]);
        }
      }
    }
  }
}

// ---------------- launch --------------------------------------------------------------

extern "C" void kernel_launch(void* const* d_in, const int* in_sizes, int n_in,
                              void* d_out, int out_size, void* d_ws, size_t ws_size,
                              hipStream_t stream) {
  const float* x     = (const float*)d_in[0];   // (256, 36, 50)
  const float* rho   = (const float*)d_in[1];   // (80,)
  const float* theta = (const float*)d_in[2];   // (80,)

  float* out    = (float*)d_out;
  float* outC   = out;                              // 256*161*50
  float* outDic = out + 256 * PDIM * NCOL;          // 36*161
  float* outR   = outDic + TDIM * PDIM;             // 256*36*50

  hipLaunchKernelGGL(dan_kernel, dim3(256), dim3(512), LDS_TOTAL, stream,
                     x, rho, theta, outC, outDic, outR);
}